// Round 1
// baseline (8701.662 us; speedup 1.0000x reference)
//
#include <hip/hip_runtime.h>
#include <cstddef>
#include <cstdint>

namespace {
constexpr int B_ = 8, C_ = 128, H_ = 128, W_ = 128;
constexpr int HW_ = H_ * W_;               // 16384
constexpr size_t CHW_ = (size_t)C_ * HW_;  // 2097152
constexpr int NPIX_ = B_ * HW_;            // 131072
}

// ---------------- weight prep: symmetrize + transpose to [i][k][o] ----------
__global__ __launch_bounds__(256) void prep_weights_k(
    const float* __restrict__ Wa, const float* __restrict__ Wb,
    float* __restrict__ Ta, float* __restrict__ Tb) {
  int idx = blockIdx.x * 256 + threadIdx.x;   // 0..802815 = i*6272 + k*128 + o
  int o = idx & 127;
  int k = (idx >> 7) % 49;
  int i = idx / (49 * 128);
  size_t oi = (size_t)o * 6272 + i * 49 + k;
  size_t io = (size_t)i * 6272 + o * 49 + k;
  Ta[idx] = 0.5f * (Wa[oi] + Wa[io]);
  Tb[idx] = 0.5f * (Wb[oi] + Wb[io]);
}

// ---------------- row sums of the 1x1 weights (for LN folding) --------------
__global__ void rowsum_k(const float* __restrict__ Wg,
                         const float* __restrict__ Wm, float* __restrict__ rs) {
  int t = threadIdx.x;  // 256 threads: 0..127 -> Wg, 128..255 -> Wm
  const float* src = (t < 128) ? Wg : Wm;
  int row = t & 127;
  float s = 0.f;
  for (int i = 0; i < 384; ++i) s += src[row * 384 + i];
  rs[t] = s;
}

// ---------------- per-pixel LN stats over 3-tensor concat (384 ch) ----------
__global__ __launch_bounds__(256) void stats3_k(
    const float* __restrict__ t0, const float* __restrict__ t1,
    const float* __restrict__ t2, float* __restrict__ mu_o,
    float* __restrict__ inv_o) {
  int q = blockIdx.x * 256 + threadIdx.x;  // 0..131071
  int b = q >> 14, p = q & (HW_ - 1);
  size_t base = (size_t)b * CHW_ + p;
  float s = 0.f, s2 = 0.f;
  for (int c = 0; c < C_; ++c) { float v = t0[base + (size_t)c * HW_]; s += v; s2 = fmaf(v, v, s2); }
  for (int c = 0; c < C_; ++c) { float v = t1[base + (size_t)c * HW_]; s += v; s2 = fmaf(v, v, s2); }
  for (int c = 0; c < C_; ++c) { float v = t2[base + (size_t)c * HW_]; s += v; s2 = fmaf(v, v, s2); }
  float m = s * (1.f / 384.f);
  float var = s2 * (1.f / 384.f) - m * m;
  mu_o[q] = m;
  inv_o[q] = rsqrtf(var + 1e-5f);
}

// ---------------- per-pixel LN stats over one tensor (128 ch) ---------------
__global__ __launch_bounds__(256) void stats1_k(
    const float* __restrict__ t0, float* __restrict__ mu_o,
    float* __restrict__ inv_o) {
  int q = blockIdx.x * 256 + threadIdx.x;
  int b = q >> 14, p = q & (HW_ - 1);
  size_t base = (size_t)b * CHW_ + p;
  float s = 0.f, s2 = 0.f;
  for (int c = 0; c < C_; ++c) { float v = t0[base + (size_t)c * HW_]; s += v; s2 = fmaf(v, v, s2); }
  float m = s * (1.f / 128.f);
  float var = s2 * (1.f / 128.f) - m * m;
  mu_o[q] = m;
  inv_o[q] = rsqrtf(var + 1e-5f);
}

// ---------------- 1x1 conv gate: GEMM (128 x 384 x 16384 per batch) ---------
// out = sigmoid( inv*(W@x - mu*rowsum) + bias ), optionally * mult (gating)
template <int GATED>
__global__ __launch_bounds__(256) void gemm1x1_k(
    const float* __restrict__ A,       // [128][384]
    const float* __restrict__ rowsum,  // [128]
    const float* __restrict__ bias,    // [128]
    const float* __restrict__ B0, const float* __restrict__ B1,
    const float* __restrict__ B2,      // concat order
    const float* __restrict__ mu, const float* __restrict__ inv,
    const float* __restrict__ mult,    // h_exc when GATED
    float* __restrict__ out) {
  __shared__ float As[16][68];
  __shared__ float Bs[16][68];
  int b = blockIdx.z;
  int m0 = blockIdx.y * 64;
  int n0 = blockIdx.x * 64;
  int tid = threadIdx.x;
  int tx = tid & 15, ty = tid >> 4;
  const float* B0b = B0 + (size_t)b * CHW_;
  const float* B1b = B1 + (size_t)b * CHW_;
  const float* B2b = B2 + (size_t)b * CHW_;
  float acc[4][4] = {};
  for (int k0 = 0; k0 < 384; k0 += 16) {
    {  // load A tile: 64 m-rows x 16 k
      int r = tid >> 2;
      int c4 = (tid & 3) * 4;
#pragma unroll
      for (int u = 0; u < 4; ++u)
        As[c4 + u][r] = A[(size_t)(m0 + r) * 384 + k0 + c4 + u];
    }
    {  // load B tile: 16 k x 64 n
      int kr = tid >> 6;
      int pc = tid & 63;
#pragma unroll
      for (int u = 0; u < 4; ++u) {
        int kk = k0 + kr + u * 4;
        const float* src = (kk < 128) ? B0b : ((kk < 256) ? B1b : B2b);
        Bs[kr + u * 4][pc] = src[(size_t)(kk & 127) * HW_ + n0 + pc];
      }
    }
    __syncthreads();
#pragma unroll
    for (int kk = 0; kk < 16; ++kk) {
      float a[4], bv[4];
#pragma unroll
      for (int i = 0; i < 4; ++i) a[i] = As[kk][ty * 4 + i];
#pragma unroll
      for (int j = 0; j < 4; ++j) bv[j] = Bs[kk][tx * 4 + j];
#pragma unroll
      for (int i = 0; i < 4; ++i)
#pragma unroll
        for (int j = 0; j < 4; ++j) acc[i][j] = fmaf(a[i], bv[j], acc[i][j]);
    }
    __syncthreads();
  }
#pragma unroll
  for (int i = 0; i < 4; ++i) {
    int m = m0 + ty * 4 + i;
    float rsm = rowsum[m], bi = bias[m];
#pragma unroll
    for (int j = 0; j < 4; ++j) {
      int p = n0 + tx * 4 + j;
      int q = b * HW_ + p;
      float val = inv[q] * (acc[i][j] - mu[q] * rsm) + bi;
      float g = 1.0f / (1.0f + __expf(-val));
      size_t oidx = (size_t)b * CHW_ + (size_t)m * HW_ + p;
      out[oidx] = GATED ? (mult[oidx] * g) : g;
    }
  }
}

// ---------------- 7x7 SAME conv, C=128 -> 128 -------------------------------
// Wt layout: [i][49][o] (symmetrized, transposed). Block: 8 out-ch x 4x128 px.
#define CONV_IC 8
__global__ __launch_bounds__(256) void conv7_k(
    const float* __restrict__ in, const float* __restrict__ Wt,
    float* __restrict__ out) {
  __shared__ float in_s[CONV_IC][10][136];
  __shared__ float w_s[CONV_IC][49][8];
  int bz = blockIdx.x;          // b*32 + ytile
  int b = bz >> 5;
  int y0 = (bz & 31) * 4;
  int o0 = blockIdx.y * 8;
  int tid = threadIdx.x;
  int x = tid & 127;
  int dy0 = (tid >> 7) * 2;     // 0 or 2
  float acc0[8] = {}, acc1[8] = {};
  for (int ic0 = 0; ic0 < 128; ic0 += CONV_IC) {
    for (int idx = tid; idx < CONV_IC * 49 * 8; idx += 256) {
      int ii = idx / (49 * 8);
      int rem = idx - ii * 49 * 8;
      int k = rem >> 3;
      int oo = rem & 7;
      w_s[ii][k][oo] = Wt[(size_t)(ic0 + ii) * 6272 + k * 128 + o0 + oo];
    }
    for (int idx = tid; idx < CONV_IC * 10 * 136; idx += 256) {
      int ii = idx / (10 * 136);
      int rem = idx - ii * 10 * 136;
      int r = rem / 136;
      int cc = rem - r * 136;
      int yy = y0 - 3 + r;
      int xx = cc - 3;
      float v = 0.0f;
      if (yy >= 0 && yy < 128 && xx >= 0 && xx < 128)
        v = in[(size_t)b * CHW_ + (size_t)(ic0 + ii) * HW_ + yy * 128 + xx];
      in_s[ii][r][cc] = v;
    }
    __syncthreads();
    for (int ii = 0; ii < CONV_IC; ++ii) {
      for (int ky = 0; ky < 7; ++ky) {
        const float* wrow = &w_s[ii][ky * 7][0];
        const float* i0 = &in_s[ii][dy0 + ky][x];
        const float* i1 = &in_s[ii][dy0 + 1 + ky][x];
#pragma unroll
        for (int kx = 0; kx < 7; ++kx) {
          float v0 = i0[kx];
          float v1 = i1[kx];
#pragma unroll
          for (int oo = 0; oo < 8; ++oo) {
            float w = wrow[kx * 8 + oo];
            acc0[oo] = fmaf(w, v0, acc0[oo]);
            acc1[oo] = fmaf(w, v1, acc1[oo]);
          }
        }
      }
    }
    __syncthreads();
  }
#pragma unroll
  for (int oo = 0; oo < 8; ++oo) {
    size_t base = (size_t)b * CHW_ + (size_t)(o0 + oo) * HW_;
    out[base + (y0 + dy0) * 128 + x] = acc0[oo];
    out[base + (y0 + dy0 + 1) * 128 + x] = acc1[oo];
  }
}

// ---------------- inhibited = relu(ff - relu((sig(alpha)*h_inh+mu)*c1)) -----
__global__ __launch_bounds__(256) void inhibit_k(
    const float* __restrict__ c1_raw, const float* __restrict__ ff,
    const float* __restrict__ h_inh, const float* __restrict__ mu_s,
    const float* __restrict__ inv_s, const float* __restrict__ alpha,
    const float* __restrict__ mu_p, const float* __restrict__ gamma,
    const float* __restrict__ beta, float* __restrict__ out) {
  size_t idx = (size_t)blockIdx.x * 256 + threadIdx.x;
  int c = (int)((idx >> 14) & 127);
  int q = (int)((idx >> 21) * HW_ + (idx & (HW_ - 1)));
  float c1 = (c1_raw[idx] - mu_s[q]) * inv_s[q] * gamma[c] + beta[c];
  float a = 1.f / (1.f + __expf(-alpha[c]));
  float t = a * h_inh[idx] + mu_p[c];
  float r = fmaxf(t * c1, 0.f);
  out[idx] = fmaxf(ff[idx] - r, 0.f);
}

// ---------------- final: LN(c2), h_tilde, convex mix ------------------------
__global__ __launch_bounds__(256) void final_k(
    float* __restrict__ io /* c2_raw in, h_exc_new out */,
    const float* __restrict__ inh, const float* __restrict__ g2,
    const float* __restrict__ h_exc, const float* __restrict__ mu_s,
    const float* __restrict__ inv_s, const float* __restrict__ gamma,
    const float* __restrict__ beta, const float* __restrict__ kappa,
    const float* __restrict__ omega) {
  size_t idx = (size_t)blockIdx.x * 256 + threadIdx.x;
  int c = (int)((idx >> 14) & 127);
  int q = (int)((idx >> 21) * HW_ + (idx & (HW_ - 1)));
  float c2 = (io[idx] - mu_s[q]) * inv_s[q] * gamma[c] + beta[c];
  float iv = inh[idx];
  float ht = fmaxf(kappa[c] * (iv + c2) + fmaxf(omega[c], 0.f) * (iv * c2), 0.f);
  float g = g2[idx];
  io[idx] = (1.f - g) * h_exc[idx] + g * ht;
}

extern "C" void kernel_launch(void* const* d_in, const int* in_sizes, int n_in,
                              void* d_out, int out_size, void* d_ws,
                              size_t ws_size, hipStream_t stream) {
  const float* ff     = (const float*)d_in[0];
  const float* h_exc  = (const float*)d_in[1];
  const float* h_inh  = (const float*)d_in[2];
  const float* W_gain = (const float*)d_in[3];
  const float* b_gain = (const float*)d_in[4];
  const float* W_mix  = (const float*)d_in[5];
  const float* b_mix  = (const float*)d_in[6];
  const float* W_inh  = (const float*)d_in[7];
  const float* W_exc  = (const float*)d_in[8];
  const float* alpha  = (const float*)d_in[9];
  const float* mu_p   = (const float*)d_in[10];
  const float* kappa  = (const float*)d_in[11];
  const float* omega  = (const float*)d_in[12];
  const float* c1_g   = (const float*)d_in[13];
  const float* c1_b   = (const float*)d_in[14];
  const float* c2_g   = (const float*)d_in[15];
  const float* c2_b   = (const float*)d_in[16];
  float* outp = (float*)d_out;

  float* w = (float*)d_ws;
  float* Wt_inh = w;  w += 802816;
  float* Wt_exc = w;  w += 802816;
  float* rs     = w;  w += 256;     // [0..127] gain, [128..255] mix
  float* mu1    = w;  w += NPIX_;
  float* inv1   = w;  w += NPIX_;
  float* mu_c1  = w;  w += NPIX_;
  float* inv_c1 = w;  w += NPIX_;
  float* mu2    = w;  w += NPIX_;
  float* inv2   = w;  w += NPIX_;
  float* mu_c2  = w;  w += NPIX_;
  float* inv_c2 = w;  w += NPIX_;
  float* bufA   = w;  w += (size_t)B_ * CHW_;  // gated -> inhibited
  float* bufB   = w;  w += (size_t)B_ * CHW_;  // c1_raw -> g2

  // 1. weight prep
  prep_weights_k<<<3136, 256, 0, stream>>>(W_inh, W_exc, Wt_inh, Wt_exc);
  rowsum_k<<<1, 256, 0, stream>>>(W_gain, W_mix, rs);
  // 2. g1 gate: LN stats + GEMM, gated = h_exc * g1
  stats3_k<<<NPIX_ / 256, 256, 0, stream>>>(h_exc, h_inh, ff, mu1, inv1);
  {
    dim3 g(256, 2, 8);
    gemm1x1_k<1><<<g, 256, 0, stream>>>(W_gain, rs, b_gain, h_exc, h_inh, ff,
                                        mu1, inv1, h_exc, bufA);
  }
  // 3. c1 = conv(gated, Ws_inh)
  {
    dim3 g(B_ * 32, 16);
    conv7_k<<<g, 256, 0, stream>>>(bufA, Wt_inh, bufB);
  }
  stats1_k<<<NPIX_ / 256, 256, 0, stream>>>(bufB, mu_c1, inv_c1);
  // 4. inhibited
  inhibit_k<<<65536, 256, 0, stream>>>(bufB, ff, h_inh, mu_c1, inv_c1, alpha,
                                       mu_p, c1_g, c1_b, bufA);
  // 5. g2 gate
  stats3_k<<<NPIX_ / 256, 256, 0, stream>>>(bufA, h_exc, h_inh, mu2, inv2);
  {
    dim3 g(256, 2, 8);
    gemm1x1_k<0><<<g, 256, 0, stream>>>(W_mix, rs + 128, b_mix, bufA, h_exc,
                                        h_inh, mu2, inv2, nullptr, bufB);
  }
  // 6. c2 = conv(inhibited, Ws_exc) -> d_out (scratch)
  {
    dim3 g(B_ * 32, 16);
    conv7_k<<<g, 256, 0, stream>>>(bufA, Wt_exc, outp);
  }
  stats1_k<<<NPIX_ / 256, 256, 0, stream>>>(outp, mu_c2, inv_c2);
  // 7. final mix (in-place on d_out)
  final_k<<<65536, 256, 0, stream>>>(outp, bufA, bufB, h_exc, mu_c2, inv_c2,
                                     c2_g, c2_b, kappa, omega);
}

// Round 2
// 1034.271 us; speedup vs baseline: 8.4133x; 8.4133x over previous
//
#include <hip/hip_runtime.h>
#include <cstddef>
#include <cstdint>

namespace {
constexpr int B_ = 8, C_ = 128, H_ = 128, W_ = 128;
constexpr int HW_ = H_ * W_;               // 16384
constexpr size_t CHW_ = (size_t)C_ * HW_;  // 2097152
constexpr int NPIX_ = B_ * HW_;            // 131072
}

typedef __attribute__((ext_vector_type(8))) short bf16x8;
typedef __attribute__((ext_vector_type(4))) float f32x4;
typedef __attribute__((ext_vector_type(8))) unsigned short u16x8;
typedef __attribute__((ext_vector_type(4))) unsigned short u16x4;

__device__ inline unsigned short f2bf(float f) {
  unsigned int u = __float_as_uint(f);
  unsigned int r = u + 0x7FFFu + ((u >> 16) & 1u);
  return (unsigned short)(r >> 16);
}

// ---- weight prep: symmetrize, cast bf16, layout [tap49][kgrp16][oc128][ic8]
__global__ __launch_bounds__(256) void prep_w_bf16_k(
    const float* __restrict__ Wa, const float* __restrict__ Wb,
    unsigned short* __restrict__ Ta, unsigned short* __restrict__ Tb) {
  int idx = blockIdx.x * 256 + threadIdx.x;  // 49*16*128*8 = 802816
  int j = idx & 7;
  int o = (idx >> 3) & 127;
  int g = (idx >> 10) & 15;
  int t = idx >> 14;           // tap 0..48
  int i = g * 8 + j;
  int ky = t / 7, kx = t - ky * 7;
  size_t oi = ((size_t)(o * 128 + i) * 7 + ky) * 7 + kx;
  size_t io = ((size_t)(i * 128 + o) * 7 + ky) * 7 + kx;
  Ta[idx] = f2bf(0.5f * (Wa[oi] + Wa[io]));
  Tb[idx] = f2bf(0.5f * (Wb[oi] + Wb[io]));
}

// ---- row sums of the 1x1 weights (LN folding) ------------------------------
__global__ void rowsum_k(const float* __restrict__ Wg,
                         const float* __restrict__ Wm, float* __restrict__ rs) {
  int t = threadIdx.x;
  const float* src = (t < 128) ? Wg : Wm;
  int row = t & 127;
  float s = 0.f;
  for (int i = 0; i < 384; ++i) s += src[row * 384 + i];
  rs[t] = s;
}

// ---- per-pixel LN stats over 3-tensor concat (384 ch) ----------------------
__global__ __launch_bounds__(256) void stats3_k(
    const float* __restrict__ t0, const float* __restrict__ t1,
    const float* __restrict__ t2, float* __restrict__ mu_o,
    float* __restrict__ inv_o) {
  int q = blockIdx.x * 256 + threadIdx.x;
  int b = q >> 14, p = q & (HW_ - 1);
  size_t base = (size_t)b * CHW_ + p;
  float s = 0.f, s2 = 0.f;
  for (int c = 0; c < C_; ++c) { float v = t0[base + (size_t)c * HW_]; s += v; s2 = fmaf(v, v, s2); }
  for (int c = 0; c < C_; ++c) { float v = t1[base + (size_t)c * HW_]; s += v; s2 = fmaf(v, v, s2); }
  for (int c = 0; c < C_; ++c) { float v = t2[base + (size_t)c * HW_]; s += v; s2 = fmaf(v, v, s2); }
  float m = s * (1.f / 384.f);
  float var = s2 * (1.f / 384.f) - m * m;
  mu_o[q] = m;
  inv_o[q] = rsqrtf(var + 1e-5f);
}

// ---- per-pixel LN stats over one tensor (128 ch) ---------------------------
__global__ __launch_bounds__(256) void stats1_k(
    const float* __restrict__ t0, float* __restrict__ mu_o,
    float* __restrict__ inv_o) {
  int q = blockIdx.x * 256 + threadIdx.x;
  int b = q >> 14, p = q & (HW_ - 1);
  size_t base = (size_t)b * CHW_ + p;
  float s = 0.f, s2 = 0.f;
  for (int c = 0; c < C_; ++c) { float v = t0[base + (size_t)c * HW_]; s += v; s2 = fmaf(v, v, s2); }
  float m = s * (1.f / 128.f);
  float var = s2 * (1.f / 128.f) - m * m;
  mu_o[q] = m;
  inv_o[q] = rsqrtf(var + 1e-5f);
}

// ---- 1x1 conv gate: GEMM; GATED=1 -> bf16 channels-last (h_exc*g1),
// ----                      GATED=0 -> f32 NCHW sigmoid
template <int GATED>
__global__ __launch_bounds__(256) void gemm1x1_k(
    const float* __restrict__ A, const float* __restrict__ rowsum,
    const float* __restrict__ bias, const float* __restrict__ B0,
    const float* __restrict__ B1, const float* __restrict__ B2,
    const float* __restrict__ mu, const float* __restrict__ inv,
    const float* __restrict__ mult, void* __restrict__ outv) {
  __shared__ float As[16][68];
  __shared__ float Bs[16][68];
  int b = blockIdx.z;
  int m0 = blockIdx.y * 64;
  int n0 = blockIdx.x * 64;
  int tid = threadIdx.x;
  int tx = tid & 15, ty = tid >> 4;
  const float* B0b = B0 + (size_t)b * CHW_;
  const float* B1b = B1 + (size_t)b * CHW_;
  const float* B2b = B2 + (size_t)b * CHW_;
  float acc[4][4] = {};
  for (int k0 = 0; k0 < 384; k0 += 16) {
    {
      int r = tid >> 2;
      int c4 = (tid & 3) * 4;
#pragma unroll
      for (int u = 0; u < 4; ++u)
        As[c4 + u][r] = A[(size_t)(m0 + r) * 384 + k0 + c4 + u];
    }
    {
      int kr = tid >> 6;
      int pc = tid & 63;
#pragma unroll
      for (int u = 0; u < 4; ++u) {
        int kk = k0 + kr + u * 4;
        const float* src = (kk < 128) ? B0b : ((kk < 256) ? B1b : B2b);
        Bs[kr + u * 4][pc] = src[(size_t)(kk & 127) * HW_ + n0 + pc];
      }
    }
    __syncthreads();
#pragma unroll
    for (int kk = 0; kk < 16; ++kk) {
      float a[4], bv[4];
#pragma unroll
      for (int i = 0; i < 4; ++i) a[i] = As[kk][ty * 4 + i];
#pragma unroll
      for (int j = 0; j < 4; ++j) bv[j] = Bs[kk][tx * 4 + j];
#pragma unroll
      for (int i = 0; i < 4; ++i)
#pragma unroll
        for (int j = 0; j < 4; ++j) acc[i][j] = fmaf(a[i], bv[j], acc[i][j]);
    }
    __syncthreads();
  }
  if (GATED) {
    unsigned short* out = (unsigned short*)outv;  // [pix][128c] bf16
#pragma unroll
    for (int j = 0; j < 4; ++j) {
      int p = n0 + tx * 4 + j;
      int q = b * HW_ + p;
      u16x4 wv;
#pragma unroll
      for (int i = 0; i < 4; ++i) {
        int m = m0 + ty * 4 + i;
        float val = inv[q] * (acc[i][j] - mu[q] * rowsum[m]) + bias[m];
        float g = 1.0f / (1.0f + __expf(-val));
        float gated = mult[(size_t)b * CHW_ + (size_t)m * HW_ + p] * g;
        wv[i] = f2bf(gated);
      }
      *(u16x4*)(out + (size_t)q * 128 + m0 + ty * 4) = wv;
    }
  } else {
    float* out = (float*)outv;  // NCHW f32
#pragma unroll
    for (int i = 0; i < 4; ++i) {
      int m = m0 + ty * 4 + i;
      float rsm = rowsum[m], bi = bias[m];
#pragma unroll
      for (int j = 0; j < 4; ++j) {
        int p = n0 + tx * 4 + j;
        int q = b * HW_ + p;
        float val = inv[q] * (acc[i][j] - mu[q] * rsm) + bi;
        out[(size_t)b * CHW_ + (size_t)m * HW_ + p] = 1.0f / (1.0f + __expf(-val));
      }
    }
  }
}

// ---- 7x7 SAME conv via MFMA bf16 --------------------------------------------
// in_cl: [B][H][W][128] bf16. Wp: [49][16][128][8] bf16. out: NCHW f32.
// Block: 512 thr = 8 waves; tile 128oc x (2 rows x 128 px). Wave: 64oc x 64px.
__global__ __launch_bounds__(512, 4) void conv7_mfma_k(
    const unsigned short* __restrict__ in_cl,
    const unsigned short* __restrict__ Wp, float* __restrict__ out) {
  __shared__ short w_s[7 * 4 * 128 * 8];   // [kx][g][oc][8] 57344 B
  __shared__ short in_s[2 * 4 * 136 * 8];  // [r][g][xi][8]  17408 B
  int b = blockIdx.x >> 6;
  int y0 = (blockIdx.x & 63) * 2;
  int tid = threadIdx.x;
  int lane = tid & 63;
  int wid = tid >> 6;
  int wm = wid >> 2;  // 0..1 -> oc half
  int wn = wid & 3;   // 0..3 -> px quarter
  int l15 = lane & 15, kg = lane >> 4;
  f32x4 acc[4][4] = {};
  for (int ky = 0; ky < 7; ++ky) {
    int ybase = y0 + ky - 3;
    for (int c4 = 0; c4 < 4; ++c4) {
      __syncthreads();
      // stage weights: 7 taps x 8KB, contiguous copies
#pragma unroll
      for (int kx = 0; kx < 7; ++kx) {
        u16x8 wv = *(const u16x8*)(Wp + (size_t)(ky * 7 + kx) * 16384 +
                                   c4 * 4096 + tid * 8);
        *(u16x8*)(w_s + kx * 4096 + tid * 8) = wv;
      }
      // stage input: 2 rows x 4 kgrp x 136 x (8 ic), zero-padded halo
      for (int u = tid; u < 1088; u += 512) {
        int r = u / 544;
        int rem = u - r * 544;
        int g = rem / 136;
        int xi = rem - g * 136;
        int x = xi - 3;
        int y = ybase + r;
        u16x8 v = {};
        if (x >= 0 && x < 128 && y >= 0 && y < 128)
          v = *(const u16x8*)(in_cl + ((size_t)((b * 128 + y) * 128 + x) * 128 +
                                       c4 * 32 + g * 8));
        *(u16x8*)(in_s + u * 8) = v;
      }
      __syncthreads();
      for (int kx = 0; kx < 7; ++kx) {
        bf16x8 bfr[4], afr[4];
#pragma unroll
        for (int nf = 0; nf < 4; ++nf) {
          int xi = (wn & 1) * 64 + nf * 16 + l15 + kx;
          bfr[nf] = *(const bf16x8*)(in_s + (((wn >> 1) * 4 + kg) * 136 + xi) * 8);
        }
#pragma unroll
        for (int mf = 0; mf < 4; ++mf) {
          int oc = wm * 64 + mf * 16 + l15;
          afr[mf] = *(const bf16x8*)(w_s + ((kx * 4 + kg) * 128 + oc) * 8);
        }
#pragma unroll
        for (int mf = 0; mf < 4; ++mf)
#pragma unroll
          for (int nf = 0; nf < 4; ++nf)
            acc[mf][nf] = __builtin_amdgcn_mfma_f32_16x16x32_bf16(
                afr[mf], bfr[nf], acc[mf][nf], 0, 0, 0);
      }
    }
  }
  int y = y0 + (wn >> 1);
  int xb = (wn & 1) * 64;
#pragma unroll
  for (int mf = 0; mf < 4; ++mf) {
    int oc = wm * 64 + mf * 16 + kg * 4;
#pragma unroll
    for (int nf = 0; nf < 4; ++nf) {
      int x = xb + nf * 16 + l15;
#pragma unroll
      for (int j = 0; j < 4; ++j)
        out[(size_t)b * CHW_ + (size_t)(oc + j) * HW_ + y * 128 + x] =
            acc[mf][nf][j];
    }
  }
}

// ---- inhibited = relu(ff - relu((sig(alpha)*h_inh+mu)*LN(c1))) --------------
// writes f32 NCHW + bf16 channels-last
__global__ __launch_bounds__(256) void inhibit_k(
    const float* __restrict__ c1_raw, const float* __restrict__ ff,
    const float* __restrict__ h_inh, const float* __restrict__ mu_s,
    const float* __restrict__ inv_s, const float* __restrict__ alpha,
    const float* __restrict__ mu_p, const float* __restrict__ gamma,
    const float* __restrict__ beta, float* __restrict__ out_f32,
    unsigned short* __restrict__ out_cl) {
  __shared__ unsigned short tile[32 * 136];  // [px][c], pad to 136
  int blk = blockIdx.x;  // 8 b x 512 tiles
  int b = blk >> 9;
  int p0 = (blk & 511) * 32;
  int t = threadIdx.x;
  int px = t & 31, cq = t >> 5;
  int q = b * HW_ + p0 + px;
  float muv = mu_s[q], invv = inv_s[q];
  size_t pixbase = (size_t)b * CHW_ + p0 + px;
  for (int ci = 0; ci < 16; ++ci) {
    int c = cq * 16 + ci;
    size_t idx = pixbase + (size_t)c * HW_;
    float c1 = (c1_raw[idx] - muv) * invv * gamma[c] + beta[c];
    float a = 1.f / (1.f + __expf(-alpha[c]));
    float r = fmaxf((a * h_inh[idx] + mu_p[c]) * c1, 0.f);
    float v = fmaxf(ff[idx] - r, 0.f);
    out_f32[idx] = v;
    tile[px * 136 + c] = f2bf(v);
  }
  __syncthreads();
#pragma unroll
  for (int pass = 0; pass < 2; ++pass) {
    int u = pass * 256 + t;
    int ppx = u >> 4, cg = u & 15;
    u16x8 v = *(const u16x8*)(tile + ppx * 136 + cg * 8);
    *(u16x8*)(out_cl + (size_t)(b * HW_ + p0 + ppx) * 128 + cg * 8) = v;
  }
}

// ---- final: LN(c2), h_tilde, convex mix; g2 in d_out -> h_new in d_out -----
__global__ __launch_bounds__(256) void final_k(
    float* __restrict__ io /* g2 in, h_new out */,
    const float* __restrict__ c2_raw, const float* __restrict__ inh,
    const float* __restrict__ h_exc, const float* __restrict__ mu_s,
    const float* __restrict__ inv_s, const float* __restrict__ gamma,
    const float* __restrict__ beta, const float* __restrict__ kappa,
    const float* __restrict__ omega) {
  size_t idx = (size_t)blockIdx.x * 256 + threadIdx.x;
  int c = (int)((idx >> 14) & 127);
  int q = (int)((idx >> 21) * HW_ + (idx & (HW_ - 1)));
  float c2 = (c2_raw[idx] - mu_s[q]) * inv_s[q] * gamma[c] + beta[c];
  float iv = inh[idx];
  float ht = fmaxf(kappa[c] * (iv + c2) + fmaxf(omega[c], 0.f) * (iv * c2), 0.f);
  float g = io[idx];
  io[idx] = (1.f - g) * h_exc[idx] + g * ht;
}

extern "C" void kernel_launch(void* const* d_in, const int* in_sizes, int n_in,
                              void* d_out, int out_size, void* d_ws,
                              size_t ws_size, hipStream_t stream) {
  const float* ff     = (const float*)d_in[0];
  const float* h_exc  = (const float*)d_in[1];
  const float* h_inh  = (const float*)d_in[2];
  const float* W_gain = (const float*)d_in[3];
  const float* b_gain = (const float*)d_in[4];
  const float* W_mix  = (const float*)d_in[5];
  const float* b_mix  = (const float*)d_in[6];
  const float* W_inh  = (const float*)d_in[7];
  const float* W_exc  = (const float*)d_in[8];
  const float* alpha  = (const float*)d_in[9];
  const float* mu_p   = (const float*)d_in[10];
  const float* kappa  = (const float*)d_in[11];
  const float* omega  = (const float*)d_in[12];
  const float* c1_g   = (const float*)d_in[13];
  const float* c1_b   = (const float*)d_in[14];
  const float* c2_g   = (const float*)d_in[15];
  const float* c2_b   = (const float*)d_in[16];

  float* w = (float*)d_ws;
  unsigned short* Wp_inh = (unsigned short*)w;  w += 401408;
  unsigned short* Wp_exc = (unsigned short*)w;  w += 401408;
  float* rs     = w;  w += 256;
  float* mu1    = w;  w += NPIX_;
  float* inv1   = w;  w += NPIX_;
  float* mu_c1  = w;  w += NPIX_;
  float* inv_c1 = w;  w += NPIX_;
  float* mu2    = w;  w += NPIX_;
  float* inv2   = w;  w += NPIX_;
  float* mu_c2  = w;  w += NPIX_;
  float* inv_c2 = w;  w += NPIX_;
  float* bufA   = w;  w += (size_t)B_ * CHW_;  // inhibited f32
  float* bufB   = w;  w += (size_t)B_ * CHW_;  // c1_raw -> c2_raw

  // channels-last bf16 scratch lives in d_out (dead before d_out's real use)
  unsigned short* gated_cl = (unsigned short*)d_out;                    // 16.7M shorts
  unsigned short* inh_cl   = (unsigned short*)d_out + (size_t)16777216; // 16.7M shorts

  prep_w_bf16_k<<<3136, 256, 0, stream>>>(W_inh, W_exc, Wp_inh, Wp_exc);
  rowsum_k<<<1, 256, 0, stream>>>(W_gain, W_mix, rs);

  // g1 gate -> gated (bf16 channels-last, into d_out lo half)
  stats3_k<<<NPIX_ / 256, 256, 0, stream>>>(h_exc, h_inh, ff, mu1, inv1);
  {
    dim3 g(256, 2, 8);
    gemm1x1_k<1><<<g, 256, 0, stream>>>(W_gain, rs, b_gain, h_exc, h_inh, ff,
                                        mu1, inv1, h_exc, (void*)gated_cl);
  }
  // c1 = sym_conv(gated)
  conv7_mfma_k<<<512, 512, 0, stream>>>(gated_cl, Wp_inh, bufB);
  stats1_k<<<NPIX_ / 256, 256, 0, stream>>>(bufB, mu_c1, inv_c1);
  // inhibited (f32 NCHW + bf16 cl into d_out hi half)
  inhibit_k<<<4096, 256, 0, stream>>>(bufB, ff, h_inh, mu_c1, inv_c1, alpha,
                                      mu_p, c1_g, c1_b, bufA, inh_cl);
  // c2 = sym_conv(inhibited) -> bufB (c1_raw dead)
  conv7_mfma_k<<<512, 512, 0, stream>>>(inh_cl, Wp_exc, bufB);
  stats1_k<<<NPIX_ / 256, 256, 0, stream>>>(bufB, mu_c2, inv_c2);
  // g2 gate -> f32 NCHW into d_out (both cl halves dead now)
  stats3_k<<<NPIX_ / 256, 256, 0, stream>>>(bufA, h_exc, h_inh, mu2, inv2);
  {
    dim3 g(256, 2, 8);
    gemm1x1_k<0><<<g, 256, 0, stream>>>(W_mix, rs + 128, b_mix, bufA, h_exc,
                                        h_inh, mu2, inv2, nullptr, d_out);
  }
  // final mix: d_out(g2) -> h_exc_new
  final_k<<<65536, 256, 0, stream>>>((float*)d_out, bufB, bufA, h_exc, mu_c2,
                                     inv_c2, c2_g, c2_b, kappa, omega);
}

// Round 3
// 778.527 us; speedup vs baseline: 11.1771x; 1.3285x over previous
//
#include <hip/hip_runtime.h>
#include <cstddef>
#include <cstdint>

namespace {
constexpr int B_ = 8, C_ = 128, H_ = 128, W_ = 128;
constexpr int HW_ = H_ * W_;               // 16384
constexpr size_t CHW_ = (size_t)C_ * HW_;  // 2097152
constexpr int NPIX_ = B_ * HW_;            // 131072
}

typedef __attribute__((ext_vector_type(8))) short bf16x8;
typedef __attribute__((ext_vector_type(4))) float f32x4;
typedef __attribute__((ext_vector_type(8))) unsigned short u16x8;
typedef __attribute__((ext_vector_type(4))) unsigned short u16x4;

__device__ inline unsigned short f2bf(float f) {
  unsigned int u = __float_as_uint(f);
  unsigned int r = u + 0x7FFFu + ((u >> 16) & 1u);
  return (unsigned short)(r >> 16);
}
__device__ inline float bf2f(unsigned short u) {
  return __uint_as_float((unsigned int)u << 16);
}

// ---- conv weight prep: symmetrize, bf16, layout [tap49][kgrp16][oc128][ic8]
__global__ __launch_bounds__(256) void prep_w_bf16_k(
    const float* __restrict__ Wa, const float* __restrict__ Wb,
    unsigned short* __restrict__ Ta, unsigned short* __restrict__ Tb) {
  int idx = blockIdx.x * 256 + threadIdx.x;  // 802816
  int j = idx & 7;
  int o = (idx >> 3) & 127;
  int g = (idx >> 10) & 15;
  int t = idx >> 14;
  int i = g * 8 + j;
  int ky = t / 7, kx = t - ky * 7;
  size_t oi = ((size_t)(o * 128 + i) * 7 + ky) * 7 + kx;
  size_t io = ((size_t)(i * 128 + o) * 7 + ky) * 7 + kx;
  Ta[idx] = f2bf(0.5f * (Wa[oi] + Wa[io]));
  Tb[idx] = f2bf(0.5f * (Wb[oi] + Wb[io]));
}

// ---- 1x1 weight prep: bf16 fragment layout [s12][f8][lane64][j8] -----------
__global__ __launch_bounds__(256) void prep_apack_k(
    const float* __restrict__ Wg, const float* __restrict__ Wm,
    unsigned short* __restrict__ Ag, unsigned short* __restrict__ Am) {
  int idx = blockIdx.x * 256 + threadIdx.x;  // 49152
  int j = idx & 7;
  int l = (idx >> 3) & 63;
  int f = (idx >> 9) & 7;
  int s = idx >> 12;
  int m = f * 16 + (l & 15);
  int k = s * 32 + (l >> 4) * 8 + j;
  Ag[idx] = f2bf(Wg[m * 384 + k]);
  Am[idx] = f2bf(Wm[m * 384 + k]);
}

// ---- row sums of the 1x1 weights, on bf16-rounded values (LN folding) ------
__global__ void rowsum_k(const float* __restrict__ Wg,
                         const float* __restrict__ Wm, float* __restrict__ rs) {
  int t = threadIdx.x;
  const float* src = (t < 128) ? Wg : Wm;
  int row = t & 127;
  float s = 0.f;
  for (int i = 0; i < 384; ++i) s += bf2f(f2bf(src[row * 384 + i]));
  rs[t] = s;
}

// ---- LN stats over 3-tensor concat + emit bf16 NCHW copies -----------------
__global__ __launch_bounds__(256) void stats3_cvt_k(
    const float* __restrict__ t0, const float* __restrict__ t1,
    const float* __restrict__ t2, float* __restrict__ mu_o,
    float* __restrict__ inv_o, unsigned short* __restrict__ o0,
    unsigned short* __restrict__ o1, unsigned short* __restrict__ o2) {
  int q = blockIdx.x * 256 + threadIdx.x;
  int b = q >> 14, p = q & (HW_ - 1);
  size_t base = (size_t)b * CHW_ + p;
  float s = 0.f, s2 = 0.f;
  for (int c = 0; c < C_; ++c) {
    size_t a = base + (size_t)c * HW_;
    float v = t0[a]; s += v; s2 = fmaf(v, v, s2); o0[a] = f2bf(v);
  }
  for (int c = 0; c < C_; ++c) {
    size_t a = base + (size_t)c * HW_;
    float v = t1[a]; s += v; s2 = fmaf(v, v, s2); o1[a] = f2bf(v);
  }
  for (int c = 0; c < C_; ++c) {
    size_t a = base + (size_t)c * HW_;
    float v = t2[a]; s += v; s2 = fmaf(v, v, s2); o2[a] = f2bf(v);
  }
  float m = s * (1.f / 384.f);
  float var = s2 * (1.f / 384.f) - m * m;
  mu_o[q] = m;
  inv_o[q] = rsqrtf(var + 1e-5f);
}

// ---- LN stats over 3 bf16 tensors ------------------------------------------
__global__ __launch_bounds__(256) void stats3_bf_k(
    const unsigned short* __restrict__ t0, const unsigned short* __restrict__ t1,
    const unsigned short* __restrict__ t2, float* __restrict__ mu_o,
    float* __restrict__ inv_o) {
  int q = blockIdx.x * 256 + threadIdx.x;
  int b = q >> 14, p = q & (HW_ - 1);
  size_t base = (size_t)b * CHW_ + p;
  float s = 0.f, s2 = 0.f;
  for (int c = 0; c < C_; ++c) { float v = bf2f(t0[base + (size_t)c * HW_]); s += v; s2 = fmaf(v, v, s2); }
  for (int c = 0; c < C_; ++c) { float v = bf2f(t1[base + (size_t)c * HW_]); s += v; s2 = fmaf(v, v, s2); }
  for (int c = 0; c < C_; ++c) { float v = bf2f(t2[base + (size_t)c * HW_]); s += v; s2 = fmaf(v, v, s2); }
  float m = s * (1.f / 384.f);
  float var = s2 * (1.f / 384.f) - m * m;
  mu_o[q] = m;
  inv_o[q] = rsqrtf(var + 1e-5f);
}

// ---- LN stats over one bf16 tensor (128 ch) --------------------------------
__global__ __launch_bounds__(256) void stats1_bf_k(
    const unsigned short* __restrict__ t0, float* __restrict__ mu_o,
    float* __restrict__ inv_o) {
  int q = blockIdx.x * 256 + threadIdx.x;
  int b = q >> 14, p = q & (HW_ - 1);
  size_t base = (size_t)b * CHW_ + p;
  float s = 0.f, s2 = 0.f;
  for (int c = 0; c < C_; ++c) { float v = bf2f(t0[base + (size_t)c * HW_]); s += v; s2 = fmaf(v, v, s2); }
  float m = s * (1.f / 128.f);
  float var = s2 * (1.f / 128.f) - m * m;
  mu_o[q] = m;
  inv_o[q] = rsqrtf(var + 1e-5f);
}

// ---- MFMA 1x1-conv gate GEMM: M=128, K=384, N=16384/batch ------------------
// FINAL=0: out = bf16-cl gated = h_exc * sigmoid(LNfold)
// FINAL=1: out = f32 NCHW h_new = (1-g2)*h_exc + g2*h_tilde(c2, inh)
template <int FINAL>
__global__ __launch_bounds__(256) void gemm_mfma_k(
    const unsigned short* __restrict__ Apack, const float* __restrict__ rowsum,
    const float* __restrict__ bias, const unsigned short* __restrict__ B0,
    const unsigned short* __restrict__ B1, const unsigned short* __restrict__ B2,
    const float* __restrict__ mu, const float* __restrict__ inv,
    const float* __restrict__ mult_f32, unsigned short* __restrict__ out_cl,
    const unsigned short* __restrict__ c2raw, const float* __restrict__ muc,
    const float* __restrict__ invc, const unsigned short* __restrict__ inh_bf,
    const float* __restrict__ h_exc, const float* __restrict__ c2g,
    const float* __restrict__ c2b, const float* __restrict__ kap,
    const float* __restrict__ omg, float* __restrict__ out_f32) {
  int b = blockIdx.y;
  int tid = threadIdx.x;
  int lane = tid & 63, wid = tid >> 6;
  int l15 = lane & 15, kg = lane >> 4;
  int n0 = blockIdx.x * 128 + wid * 32;
  size_t bofs = (size_t)b * CHW_;
  f32x4 acc[8][2] = {};
  for (int s = 0; s < 12; ++s) {
    const unsigned short* src = (s < 4) ? B0 : ((s < 8) ? B1 : B2);
    const unsigned short* bp =
        src + bofs + (size_t)((s & 3) * 32 + kg * 8) * HW_ + n0 + l15;
    bf16x8 bfr[2];
#pragma unroll
    for (int nf = 0; nf < 2; ++nf) {
      const unsigned short* qp = bp + nf * 16;
      bf16x8 v;
      v[0] = (short)qp[0];
      v[1] = (short)qp[HW_];
      v[2] = (short)qp[2 * HW_];
      v[3] = (short)qp[3 * HW_];
      v[4] = (short)qp[4 * HW_];
      v[5] = (short)qp[5 * HW_];
      v[6] = (short)qp[6 * HW_];
      v[7] = (short)qp[7 * HW_];
      bfr[nf] = v;
    }
    const bf16x8* ap = (const bf16x8*)(Apack + ((size_t)(s * 8) * 64 + lane) * 8);
#pragma unroll
    for (int f = 0; f < 8; ++f) {
      bf16x8 afr = ap[f * 64];
#pragma unroll
      for (int nf = 0; nf < 2; ++nf)
        acc[f][nf] = __builtin_amdgcn_mfma_f32_16x16x32_bf16(afr, bfr[nf],
                                                             acc[f][nf], 0, 0, 0);
    }
  }
#pragma unroll
  for (int nf = 0; nf < 2; ++nf) {
    int n = n0 + nf * 16 + l15;
    int qpix = b * HW_ + n;
    float muv = mu[qpix], invv = inv[qpix];
    if (!FINAL) {
#pragma unroll
      for (int mf = 0; mf < 8; ++mf) {
        int m0 = mf * 16 + kg * 4;
        f32x4 rs4 = *(const f32x4*)(rowsum + m0);
        f32x4 bi4 = *(const f32x4*)(bias + m0);
        u16x4 st;
#pragma unroll
        for (int j = 0; j < 4; ++j) {
          float val = invv * (acc[mf][nf][j] - muv * rs4[j]) + bi4[j];
          float g = 1.f / (1.f + __expf(-val));
          float h = mult_f32[bofs + (size_t)(m0 + j) * HW_ + n];
          st[j] = f2bf(h * g);
        }
        *(u16x4*)(out_cl + (size_t)qpix * 128 + m0) = st;
      }
    } else {
      float mcv = muc[qpix], icv = invc[qpix];
#pragma unroll
      for (int mf = 0; mf < 8; ++mf) {
        int m0 = mf * 16 + kg * 4;
        f32x4 rs4 = *(const f32x4*)(rowsum + m0);
        f32x4 bi4 = *(const f32x4*)(bias + m0);
        f32x4 g4 = *(const f32x4*)(c2g + m0);
        f32x4 b4 = *(const f32x4*)(c2b + m0);
        f32x4 k4 = *(const f32x4*)(kap + m0);
        f32x4 o4 = *(const f32x4*)(omg + m0);
#pragma unroll
        for (int j = 0; j < 4; ++j) {
          size_t idx = bofs + (size_t)(m0 + j) * HW_ + n;
          float val = invv * (acc[mf][nf][j] - muv * rs4[j]) + bi4[j];
          float g2 = 1.f / (1.f + __expf(-val));
          float c2 = (bf2f(c2raw[idx]) - mcv) * icv * g4[j] + b4[j];
          float iv = bf2f(inh_bf[idx]);
          float ht =
              fmaxf(k4[j] * (iv + c2) + fmaxf(o4[j], 0.f) * (iv * c2), 0.f);
          out_f32[idx] = (1.f - g2) * h_exc[idx] + g2 * ht;
        }
      }
    }
  }
}

// ---- 7x7 SAME conv via MFMA bf16, output bf16 NCHW --------------------------
__global__ __launch_bounds__(512, 4) void conv7_mfma_k(
    const unsigned short* __restrict__ in_cl,
    const unsigned short* __restrict__ Wp, unsigned short* __restrict__ out) {
  __shared__ short w_s[7 * 4 * 128 * 8];   // 57344 B
  __shared__ short in_s[2 * 4 * 136 * 8];  // 17408 B
  int b = blockIdx.x >> 6;
  int y0 = (blockIdx.x & 63) * 2;
  int tid = threadIdx.x;
  int lane = tid & 63;
  int wid = tid >> 6;
  int wm = wid >> 2;
  int wn = wid & 3;
  int l15 = lane & 15, kg = lane >> 4;
  f32x4 acc[4][4] = {};
  for (int ky = 0; ky < 7; ++ky) {
    int ybase = y0 + ky - 3;
    for (int c4 = 0; c4 < 4; ++c4) {
      __syncthreads();
#pragma unroll
      for (int kx = 0; kx < 7; ++kx) {
        u16x8 wv = *(const u16x8*)(Wp + (size_t)(ky * 7 + kx) * 16384 +
                                   c4 * 4096 + tid * 8);
        *(u16x8*)(w_s + kx * 4096 + tid * 8) = wv;
      }
      for (int u = tid; u < 1088; u += 512) {
        int r = u / 544;
        int rem = u - r * 544;
        int g = rem / 136;
        int xi = rem - g * 136;
        int x = xi - 3;
        int y = ybase + r;
        u16x8 v = {};
        if (x >= 0 && x < 128 && y >= 0 && y < 128)
          v = *(const u16x8*)(in_cl + ((size_t)((b * 128 + y) * 128 + x) * 128 +
                                       c4 * 32 + g * 8));
        *(u16x8*)(in_s + u * 8) = v;
      }
      __syncthreads();
      for (int kx = 0; kx < 7; ++kx) {
        bf16x8 bfr[4], afr[4];
#pragma unroll
        for (int nf = 0; nf < 4; ++nf) {
          int xi = (wn & 1) * 64 + nf * 16 + l15 + kx;
          bfr[nf] = *(const bf16x8*)(in_s + (((wn >> 1) * 4 + kg) * 136 + xi) * 8);
        }
#pragma unroll
        for (int mf = 0; mf < 4; ++mf) {
          int oc = wm * 64 + mf * 16 + l15;
          afr[mf] = *(const bf16x8*)(w_s + ((kx * 4 + kg) * 128 + oc) * 8);
        }
#pragma unroll
        for (int mf = 0; mf < 4; ++mf)
#pragma unroll
          for (int nf = 0; nf < 4; ++nf)
            acc[mf][nf] = __builtin_amdgcn_mfma_f32_16x16x32_bf16(
                afr[mf], bfr[nf], acc[mf][nf], 0, 0, 0);
      }
    }
  }
  int y = y0 + (wn >> 1);
  int xb = (wn & 1) * 64;
#pragma unroll
  for (int mf = 0; mf < 4; ++mf) {
    int oc = wm * 64 + mf * 16 + kg * 4;
#pragma unroll
    for (int nf = 0; nf < 4; ++nf) {
      int x = xb + nf * 16 + l15;
#pragma unroll
      for (int j = 0; j < 4; ++j)
        out[(size_t)b * CHW_ + (size_t)(oc + j) * HW_ + y * 128 + x] =
            f2bf(acc[mf][nf][j]);
    }
  }
}

// ---- inhibited = relu(ff - relu((sig(alpha)*h_inh+mu)*LN(c1))) --------------
// in: c1_raw bf16 NCHW; out: bf16 NCHW + bf16 channels-last
__global__ __launch_bounds__(256) void inhibit_k(
    const unsigned short* __restrict__ c1_raw_bf, const float* __restrict__ ff,
    const float* __restrict__ h_inh, const float* __restrict__ mu_s,
    const float* __restrict__ inv_s, const float* __restrict__ alpha,
    const float* __restrict__ mu_p, const float* __restrict__ gamma,
    const float* __restrict__ beta, unsigned short* __restrict__ out_nchw,
    unsigned short* __restrict__ out_cl) {
  __shared__ unsigned short tile[32 * 136];
  int blk = blockIdx.x;
  int b = blk >> 9;
  int p0 = (blk & 511) * 32;
  int t = threadIdx.x;
  int px = t & 31, cq = t >> 5;
  int q = b * HW_ + p0 + px;
  float muv = mu_s[q], invv = inv_s[q];
  size_t pixbase = (size_t)b * CHW_ + p0 + px;
  for (int ci = 0; ci < 16; ++ci) {
    int c = cq * 16 + ci;
    size_t idx = pixbase + (size_t)c * HW_;
    float c1 = (bf2f(c1_raw_bf[idx]) - muv) * invv * gamma[c] + beta[c];
    float a = 1.f / (1.f + __expf(-alpha[c]));
    float r = fmaxf((a * h_inh[idx] + mu_p[c]) * c1, 0.f);
    float v = fmaxf(ff[idx] - r, 0.f);
    unsigned short bv = f2bf(v);
    out_nchw[idx] = bv;
    tile[px * 136 + c] = bv;
  }
  __syncthreads();
#pragma unroll
  for (int pass = 0; pass < 2; ++pass) {
    int u = pass * 256 + t;
    int ppx = u >> 4, cg = u & 15;
    u16x8 v = *(const u16x8*)(tile + ppx * 136 + cg * 8);
    *(u16x8*)(out_cl + (size_t)(b * HW_ + p0 + ppx) * 128 + cg * 8) = v;
  }
}

extern "C" void kernel_launch(void* const* d_in, const int* in_sizes, int n_in,
                              void* d_out, int out_size, void* d_ws,
                              size_t ws_size, hipStream_t stream) {
  const float* ff     = (const float*)d_in[0];
  const float* h_exc  = (const float*)d_in[1];
  const float* h_inh  = (const float*)d_in[2];
  const float* W_gain = (const float*)d_in[3];
  const float* b_gain = (const float*)d_in[4];
  const float* W_mix  = (const float*)d_in[5];
  const float* b_mix  = (const float*)d_in[6];
  const float* W_inh  = (const float*)d_in[7];
  const float* W_exc  = (const float*)d_in[8];
  const float* alpha  = (const float*)d_in[9];
  const float* mu_p   = (const float*)d_in[10];
  const float* kappa  = (const float*)d_in[11];
  const float* omega  = (const float*)d_in[12];
  const float* c1_g   = (const float*)d_in[13];
  const float* c1_b   = (const float*)d_in[14];
  const float* c2_g   = (const float*)d_in[15];
  const float* c2_b   = (const float*)d_in[16];

  float* w = (float*)d_ws;
  unsigned short* Wp_inh = (unsigned short*)w;  w += 401408;
  unsigned short* Wp_exc = (unsigned short*)w;  w += 401408;
  unsigned short* Ag     = (unsigned short*)w;  w += 24576;
  unsigned short* Am     = (unsigned short*)w;  w += 24576;
  float* rs     = w;  w += 256;
  float* mu1    = w;  w += NPIX_;
  float* inv1   = w;  w += NPIX_;
  float* mu_c1  = w;  w += NPIX_;
  float* inv_c1 = w;  w += NPIX_;
  float* mu2    = w;  w += NPIX_;
  float* inv2   = w;  w += NPIX_;
  float* mu_c2  = w;  w += NPIX_;
  float* inv_c2 = w;  w += NPIX_;
  unsigned short* exc_bf   = (unsigned short*)w;  w += 8388608;
  unsigned short* hinh_bf  = (unsigned short*)w;  w += 8388608;
  unsigned short* ffinh_bf = (unsigned short*)w;  w += 8388608;  // ff, then inhibited
  unsigned short* conv_bf  = (unsigned short*)w;  w += 8388608;  // c1_raw, then c2_raw

  unsigned short* gated_cl = (unsigned short*)d_out;
  unsigned short* inh_cl   = (unsigned short*)d_out + (size_t)16777216;

  prep_w_bf16_k<<<3136, 256, 0, stream>>>(W_inh, W_exc, Wp_inh, Wp_exc);
  prep_apack_k<<<192, 256, 0, stream>>>(W_gain, W_mix, Ag, Am);
  rowsum_k<<<1, 256, 0, stream>>>(W_gain, W_mix, rs);

  // g1 gate inputs: LN stats + bf16 copies
  stats3_cvt_k<<<512, 256, 0, stream>>>(h_exc, h_inh, ff, mu1, inv1, exc_bf,
                                        hinh_bf, ffinh_bf);
  // gated = h_exc * g1  (bf16 channels-last into d_out lo)
  {
    dim3 g(128, 8);
    gemm_mfma_k<0><<<g, 256, 0, stream>>>(
        Ag, rs, b_gain, exc_bf, hinh_bf, ffinh_bf, mu1, inv1, h_exc, gated_cl,
        nullptr, nullptr, nullptr, nullptr, nullptr, nullptr, nullptr, nullptr,
        nullptr, nullptr);
  }
  // c1 = sym_conv(gated)
  conv7_mfma_k<<<512, 512, 0, stream>>>(gated_cl, Wp_inh, conv_bf);
  stats1_bf_k<<<512, 256, 0, stream>>>(conv_bf, mu_c1, inv_c1);
  // inhibited -> bf16 NCHW (aliases ff_bf, dead) + bf16 cl (d_out hi)
  inhibit_k<<<4096, 256, 0, stream>>>(conv_bf, ff, h_inh, mu_c1, inv_c1, alpha,
                                      mu_p, c1_g, c1_b, ffinh_bf, inh_cl);
  // g2 stats on bf16 copies
  stats3_bf_k<<<512, 256, 0, stream>>>(ffinh_bf, exc_bf, hinh_bf, mu2, inv2);
  // c2 = sym_conv(inhibited)
  conv7_mfma_k<<<512, 512, 0, stream>>>(inh_cl, Wp_exc, conv_bf);
  stats1_bf_k<<<512, 256, 0, stream>>>(conv_bf, mu_c2, inv_c2);
  // g2 gemm + fused final mix -> d_out f32 NCHW
  {
    dim3 g(128, 8);
    gemm_mfma_k<1><<<g, 256, 0, stream>>>(
        Am, rs + 128, b_mix, ffinh_bf, exc_bf, hinh_bf, mu2, inv2, nullptr,
        nullptr, conv_bf, mu_c2, inv_c2, ffinh_bf, h_exc, c2_g, c2_b, kappa,
        omega, (float*)d_out);
  }
}